// Round 8
// baseline (45.156 us; speedup 1.0000x reference)
//
#include <hip/hip_runtime.h>
#include <math.h>
#include <utility>

#define DIMS  16
#define BATCH 32768
#define NPAIR 136
#define NMT   5        // M-tiles of 32 (rows 0..159)
#define NKK   10       // K-steps of 16 (K = 160)
#define A_ELEMS (NKK*NMT*64*8)   // 25600 bf16, fragment-sliced

typedef short s16x8  __attribute__((ext_vector_type(8)));
typedef float f32x16 __attribute__((ext_vector_type(16)));

// ---------- compile-time combinatorics (lex = combinations_with_replacement) ----------
constexpr int pairlex(int i0, int i1){ int s=0; for(int j=0;j<i0;++j) s+=(DIMS-j); return s+(i1-i0); }
constexpr int pid_i0(int pid){ int i0=0,rem=pid; while(rem>=DIMS-i0){rem-=DIMS-i0;++i0;} return i0; }
constexpr int pid_i1(int pid){ int i0=0,rem=pid; while(rem>=DIMS-i0){rem-=DIMS-i0;++i0;} return i0+rem; }
constexpr int cnt3(int j){ return (DIMS-j)*(DIMS+1-j)/2; }
constexpr int off3(int i0){ int s=0; for(int j=0;j<i0;++j) s+=cnt3(j); return s; }
constexpr int cnt4j(int j){ return (DIMS-j)*(DIMS+1-j)*(DIMS+2-j)/6; }
constexpr int off4(int i0){ int s=0; for(int j=0;j<i0;++j) s+=cnt4j(j); return s; }
// W layout: [0]=const, [1..16]=deg1, [17..152]=deg2, [153..968]=deg3, [969..4844]=deg4
constexpr int w3rowbase(int i0){ return 1+DIMS+NPAIR+off3(i0); }
constexpr int w4base(int i0,int i1){ int s=off4(i0); for(int b=i0;b<i1;++b) s+=cnt3(b); return 1+DIMS+NPAIR+816+s; }
static_assert(pairlex(15,15)==135 && off3(DIMS)==816 && off4(DIMS)==3876, "combi");
static_assert(w4base(15,15)==4844, "wtail");

// ---------- row metadata (r3..r7-verified) ----------
struct RowMeta { short qs, qe, wb, deg; };
struct RowTab  { RowMeta m[NMT*32]; };
constexpr RowTab make_rowtab(){
    RowTab t{};
    for (int r = 0; r < NMT*32; ++r) {
        RowMeta rm{0,0,0,0};
        if (r < NPAIR) {
            int i0 = pid_i0(r), i1 = pid_i1(r);
            rm = RowMeta{ (short)pairlex(i1,i1), (short)NPAIR, (short)w4base(i0,i1), 4 };
        } else if (r < NPAIR + DIMS) {
            int i0 = r - NPAIR;
            rm = RowMeta{ (short)pairlex(i0,i0), (short)NPAIR, (short)w3rowbase(i0), 3 };
        } else if (r == 152) {
            rm = RowMeta{ 0, (short)NPAIR, (short)(1+DIMS), 2 };
        } else if (r == 153) {
            rm = RowMeta{ (short)NPAIR, (short)(NPAIR+DIMS), 1, 1 };
        }
        t.m[r] = rm;
    }
    return t;
}

// ---------- DESC: A-slot (fragment layout) -> (deg<<13 | W index); 0 => zero ----------
struct DescT { unsigned short d[A_ELEMS]; };
constexpr DescT make_desc(){
    DescT D{};
    const RowTab rt = make_rowtab();
    for (int id = 0; id < A_ELEMS; ++id) {
        const int e = id & 7, ln = (id >> 3) & 63, mtkk = id >> 9;
        const int mt = mtkk % NMT, kk = mtkk / NMT;
        const int row = mt*32 + (ln & 31);
        const int k   = kk*16 + 4*(ln >> 5) + (e & 3) + 8*(e >> 2);
        const RowMeta rm = rt.m[row];
        unsigned short v = 0;
        if (k >= rm.qs && k < rm.qe)
            v = (unsigned short)(((unsigned)rm.deg << 13) | (unsigned)(rm.wb + k - rm.qs));
        D.d[id] = v;
    }
    return D;
}
__device__ __constant__ DescT DESC = make_desc();

// ---------- helpers ----------
__device__ __forceinline__ ushort f2bf(float f){
    union { float f; unsigned u; } v{f};
    return (ushort)((v.u + 0x7FFF + ((v.u >> 16) & 1)) >> 16);   // RNE
}
__device__ __forceinline__ unsigned packbf(float a, float b){    // RNE pack of 2 bf16
    const unsigned ua = __float_as_uint(a) + 0x8000u;
    const unsigned ub = __float_as_uint(b) + 0x8000u;
    return (ua >> 16) | (ub & 0xFFFF0000u);
}

template<typename F, int... Is>
__device__ __forceinline__ void sfor_impl(F&& f, std::integer_sequence<int,Is...>){
    (f(std::integral_constant<int,Is>{}), ...);
}
template<int N, typename F>
__device__ __forceinline__ void sfor(F&& f){
    sfor_impl(static_cast<F&&>(f), std::make_integer_sequence<int,N>{});
}

// F row value (static row -> static xv indices)
template<int R>
__device__ __forceinline__ float fval(const float (&xv)[DIMS]){
    if constexpr      (R < NPAIR)        return xv[pid_i0(R)] * xv[pid_i1(R)];
    else if constexpr (R < NPAIR+DIMS)   return xv[R - NPAIR];
    else if constexpr (R < 154)          return 1.0f;
    else                                 return 0.0f;
}

template<int M>
__device__ __forceinline__ f32x16& pick(f32x16& a0, f32x16& a1, f32x16& a2,
                                        f32x16& a3, f32x16& a4){
    if constexpr (M == 0) return a0;
    else if constexpr (M == 1) return a1;
    else if constexpr (M == 2) return a2;
    else if constexpr (M == 3) return a3;
    else return a4;
}

// ---------- kernel 1: build gated A (sample-independent) into d_ws (r6/r7-verified) ----------
__global__ __launch_bounds__(256)
void build_A_kernel(const float* __restrict__ W, const float* __restrict__ M_raw,
                    unsigned* __restrict__ A_ws)
{
    const int t = blockIdx.x*256 + threadIdx.x;          // 0..12799
    const float M  = 3.0f/(1.0f+__expf(-M_raw[0])) + 1.0f;
    const float g1 = 1.0f/(1.0f+__expf(-10.0f*(M-0.5f)));
    const float g2 = 1.0f/(1.0f+__expf(-10.0f*(M-1.5f)));
    const float g3 = 1.0f/(1.0f+__expf(-10.0f*(M-2.5f)));
    const float g4 = 1.0f/(1.0f+__expf(-10.0f*(M-3.5f)));

    const unsigned d  = reinterpret_cast<const unsigned*>(DESC.d)[t];
    const unsigned d0 = d & 0xFFFFu, d1 = d >> 16;
    const int deg0 = d0 >> 13, deg1 = d1 >> 13;
    const float gv0 = deg0==4?g4 : deg0==3?g3 : deg0==2?g2 : deg0==1?g1 : 0.0f;
    const float gv1 = deg1==4?g4 : deg1==3?g3 : deg1==2?g2 : deg1==1?g1 : 0.0f;
    const float v0 = gv0 * W[d0 & 0x1FFF];
    const float v1 = gv1 * W[d1 & 0x1FFF];
    A_ws[t] = (unsigned)f2bf(v0) | ((unsigned)f2bf(v1) << 16);
}

// ---------- kernel 2: solo waves. 1 wave = 32 samples. NO LDS, NO barriers. ----------
// F in registers (bfw, r6-verified packing); A-frags straight from L2-resident global;
// 5 independent acc chains for ILP; in-register epilogue (r6-verified algebra).
__global__ __launch_bounds__(64, 1)
void poly_logreg_solo(const float* __restrict__ x, const float* __restrict__ W,
                      const float* __restrict__ b, const unsigned* __restrict__ A_ws,
                      float* __restrict__ out)
{
    const int lane = threadIdx.x;            // 0..63
    const int col  = lane & 31;
    const bool hs  = lane >= 32;
    const size_t s0 = (size_t)blockIdx.x * 32;

    // ---- x for this lane's sample (both halves load the same 32 samples) ----
    const float4* xp = reinterpret_cast<const float4*>(x + (s0 + col)*DIMS);
    const float4 xa = xp[0], xb = xp[1], xc = xp[2], xd = xp[3];
    float xv[DIMS];
    xv[0]=xa.x; xv[1]=xa.y; xv[2]=xa.z; xv[3]=xa.w;
    xv[4]=xb.x; xv[5]=xb.y; xv[6]=xb.z; xv[7]=xb.w;
    xv[8]=xc.x; xv[9]=xc.y; xv[10]=xc.z; xv[11]=xc.w;
    xv[12]=xd.x; xv[13]=xd.y; xv[14]=xd.z; xv[15]=xd.w;

    // ---- F-build into packed B-frag registers (r6-verified) ----
    unsigned bfw[NKK][4];
    sfor<NKK>([&](auto K){ constexpr int kk = decltype(K)::value;
        sfor<4>([&](auto J){ constexpr int j = decltype(J)::value;
            constexpr int e0 = 2*j, e1 = 2*j + 1;
            constexpr int r0a = 16*kk + (e0 & 3) + 8*(e0 >> 2);
            constexpr int r0b = 16*kk + (e1 & 3) + 8*(e1 >> 2);
            const float va = hs ? fval<r0a+4>(xv) : fval<r0a>(xv);
            const float vb = hs ? fval<r0b+4>(xv) : fval<r0b>(xv);
            bfw[kk][j] = packbf(va, vb);
        });
    });

    // ---- 5 independent MFMA chains; A-frags read directly from global (L2-hot) ----
    const ushort* Ap = reinterpret_cast<const ushort*>(A_ws);
    f32x16 a0{}, a1{}, a2{}, a3{}, a4{};
    sfor<NKK>([&](auto K){ constexpr int kk = decltype(K)::value;
        union { unsigned u[4]; s16x8 v; } bu;
        bu.u[0]=bfw[kk][0]; bu.u[1]=bfw[kk][1]; bu.u[2]=bfw[kk][2]; bu.u[3]=bfw[kk][3];
        sfor<NMT>([&](auto Mc){ constexpr int mt = decltype(Mc)::value;
            const s16x8 af = *reinterpret_cast<const s16x8*>(
                Ap + (size_t)((kk*NMT + mt)*64 + lane)*8);
            f32x16& acc = pick<mt>(a0, a1, a2, a3, a4);
            acc = __builtin_amdgcn_mfma_f32_32x32x16_bf16(af, bu.v, acc, 0, 0, 0);
        });
    });

    // ---- in-register epilogue (r6-verified): mult = F[32mt+crow][col] from own bfw ----
    float ptot = 0.0f;
    sfor<NMT>([&](auto Mc){ constexpr int mt = decltype(Mc)::value;
        const f32x16& acc = pick<mt>(a0, a1, a2, a3, a4);
        float p = 0.0f;
        sfor<16>([&](auto R){ constexpr int reg = decltype(R)::value;
            constexpr int kksel = 2*mt + (reg >> 3);
            constexpr int word  = ((reg & 3) >> 1) + 2*((reg >> 2) & 1);
            const unsigned w = bfw[kksel][word];
            const float mult = __uint_as_float((reg & 1) ? (w & 0xFFFF0000u) : (w << 16));
            p = fmaf(mult, acc[reg], p);
        });
        p += __shfl_xor(p, 32);          // combine the two h-halves (row sets)
        ptot += p;
    });

    if (!hs) {
        const float logit = ptot + W[0] + b[0];
        out[s0 + col] = 1.0f/(1.0f+__expf(-logit));
    }
}

extern "C" void kernel_launch(void* const* d_in, const int* in_sizes, int n_in,
                              void* d_out, int out_size, void* d_ws, size_t ws_size,
                              hipStream_t stream)
{
    const float* x     = (const float*)d_in[0];
    const float* W     = (const float*)d_in[1];
    const float* b     = (const float*)d_in[2];
    const float* M_raw = (const float*)d_in[3];
    float* out = (float*)d_out;
    unsigned* A_ws = (unsigned*)d_ws;            // 51200 B

    build_A_kernel<<<A_ELEMS/512, 256, 0, stream>>>(W, M_raw, A_ws);
    poly_logreg_solo<<<BATCH/32, 64, 0, stream>>>(x, W, b, A_ws, out);
}

// Round 9
// 17.043 us; speedup vs baseline: 2.6496x; 2.6496x over previous
//
#include <hip/hip_runtime.h>
#include <math.h>
#include <utility>

#define DIMS  16
#define BATCH 32768
#define NPAIR 136
#define NROLE 16

// ---------- compile-time combinatorics (lex = combinations_with_replacement; r2-verified) ----------
constexpr int pairlex(int i0, int i1){ int s=0; for(int j=0;j<i0;++j) s+=(DIMS-j); return s+(i1-i0); }
constexpr int pid_i0(int pid){ int i0=0,rem=pid; while(rem>=DIMS-i0){rem-=DIMS-i0;++i0;} return i0; }
constexpr int pid_i1(int pid){ int i0=0,rem=pid; while(rem>=DIMS-i0){rem-=DIMS-i0;++i0;} return i0+rem; }
constexpr int cnt3(int j){ return (DIMS-j)*(DIMS+1-j)/2; }
constexpr int off3(int i0){ int s=0; for(int j=0;j<i0;++j) s+=cnt3(j); return s; }
constexpr int cnt4j(int j){ return (DIMS-j)*(DIMS+1-j)*(DIMS+2-j)/6; }
constexpr int off4(int i0){ int s=0; for(int j=0;j<i0;++j) s+=cnt4j(j); return s; }
// W layout: [0]=const, [1..16]=deg1, [17..152]=deg2, [153..968]=deg3, [969..4844]=deg4
constexpr int w2idx(int i0,int i1){ return 1+DIMS+pairlex(i0,i1); }
constexpr int w3base(int i0,int i1){ int s=off3(i0); for(int b=i0;b<i1;++b) s+=(DIMS-b); return 1+DIMS+NPAIR+s; }
constexpr int w4base(int i0,int i1){ int s=off4(i0); for(int b=i0;b<i1;++b) s+=cnt3(b); return 1+DIMS+NPAIR+816+s; }
static_assert(pairlex(15,15)==135 && off3(DIMS)==816 && off4(DIMS)==3876, "combi");
static_assert(w3base(15,15)==968 && w4base(15,15)==4844, "wtail");

// ---------- LPT partition of the 136 pairs into 16 balanced roles (~378 FMA each) ----------
constexpr int costv(int v){ return (DIMS-v) + (DIMS+1-v)*(DIMS+2-v)/2 + 3; }
struct Plan { int role_of[NPAIR]; };
constexpr Plan make_plan(){
    Plan p{}; long load[NROLE]={};
    for(int v=0; v<DIMS; ++v)                      // costv descends in v -> LPT order
        for(int i0=0; i0<=v; ++i0){
            int best=0;
            for(int r=1;r<NROLE;++r) if(load[r]<load[best]) best=r;
            p.role_of[pairlex(i0,v)]=best;
            load[best]+=costv(v);
        }
    return p;
}
inline constexpr Plan PLAN = make_plan();

// ---------- static_for ----------
template<typename F, int... Is>
__device__ __forceinline__ void sfor_impl(F&& f, std::integer_sequence<int,Is...>){
    (f(std::integral_constant<int,Is>{}), ...);
}
template<int N, typename F>
__device__ __forceinline__ void sfor(F&& f){
    sfor_impl(static_cast<F&&>(f), std::make_integer_sequence<int,N>{});
}

// ---------- per-pair body (r2-verified math): W via uniform ptr + constexpr offsets -> s_load ----------
template<int I0, int I1>
__device__ __forceinline__ void do_pair(const float* __restrict__ W,
                                        const float (&xv)[DIMS],
                                        float& a2, float& a3, float& a4)
{
    constexpr int KW2 = w2idx(I0, I1);
    constexpr int KW3 = w3base(I0, I1);
    constexpr int KW4 = w4base(I0, I1);

    const float p2 = xv[I0] * xv[I1];
    a2 = fmaf(W[KW2], p2, a2);

    float s3 = 0.f;
    sfor<DIMS - I1>([&](auto J){ constexpr int j = decltype(J)::value;
        s3 = fmaf(W[KW3 + j], xv[I1 + j], s3); });
    a3 = fmaf(p2, s3, a3);

    float t = 0.f;
    sfor<DIMS - I1>([&](auto I){ constexpr int i2 = I1 + decltype(I)::value;
        constexpr int base = KW4 + ((DIMS - I1) + (DIMS + 1 - i2)) * (i2 - I1) / 2;
        float s4 = 0.f;
        sfor<DIMS - i2>([&](auto K){ constexpr int i3 = i2 + decltype(K)::value;
            s4 = fmaf(W[base + (i3 - i2)], xv[i3], s4); });
        t = fmaf(xv[i2], s4, t); });
    a4 = fmaf(p2, t, a4);
}

template<int R>
__device__ __forceinline__ float role_body(const float* __restrict__ W,
                                           const float (&xv)[DIMS],
                                           float w2, float w3, float w4)
{
    float a2 = 0.f, a3 = 0.f, a4 = 0.f;
    sfor<NPAIR>([&](auto P){ constexpr int pid = decltype(P)::value;
        if constexpr (PLAN.role_of[pid] == R)
            do_pair<pid_i0(pid), pid_i1(pid)>(W, xv, a2, a3, a4); });
    return fmaf(w2, a2, fmaf(w3, a3, w4 * a4));
}

// ---------- kernel 1: one role per block. 1024 thr = 16 waves, all same ~3.5KB body ----------
// I$: one body/block (2 bodies/CU). K$: ~1.5KB W-slice/block, shared by 16 waves.
// 512 blocks -> 2 blocks/CU -> 32 waves/CU. ~30 VGPR, no LDS, no spill surface.
__global__ __launch_bounds__(1024, 8)
void role_kernel(const float* __restrict__ x, const float* __restrict__ W,
                 const float* __restrict__ M_raw, float* __restrict__ part)
{
    const int role = blockIdx.x & (NROLE - 1);
    const int s    = (blockIdx.x >> 4) * 1024 + threadIdx.x;

    // x for this sample (coalesced float4 x4)
    const float4* xp = reinterpret_cast<const float4*>(x + (size_t)s * DIMS);
    const float4 xa = xp[0], xb = xp[1], xc = xp[2], xd = xp[3];

    // degree gates (uniform)
    const float M  = 3.0f/(1.0f+__expf(-M_raw[0])) + 1.0f;
    const float w2 = 1.0f/(1.0f+__expf(-10.0f*(M-1.5f)));
    const float w3 = 1.0f/(1.0f+__expf(-10.0f*(M-2.5f)));
    const float w4 = 1.0f/(1.0f+__expf(-10.0f*(M-3.5f)));

    float xv[DIMS];
    xv[0]=xa.x; xv[1]=xa.y; xv[2]=xa.z; xv[3]=xa.w;
    xv[4]=xb.x; xv[5]=xb.y; xv[6]=xb.z; xv[7]=xb.w;
    xv[8]=xc.x; xv[9]=xc.y; xv[10]=xc.z; xv[11]=xc.w;
    xv[12]=xd.x; xv[13]=xd.y; xv[14]=xd.z; xv[15]=xd.w;

    float p;
    switch (role) {
        case 0:  p = role_body<0 >(W, xv, w2, w3, w4); break;
        case 1:  p = role_body<1 >(W, xv, w2, w3, w4); break;
        case 2:  p = role_body<2 >(W, xv, w2, w3, w4); break;
        case 3:  p = role_body<3 >(W, xv, w2, w3, w4); break;
        case 4:  p = role_body<4 >(W, xv, w2, w3, w4); break;
        case 5:  p = role_body<5 >(W, xv, w2, w3, w4); break;
        case 6:  p = role_body<6 >(W, xv, w2, w3, w4); break;
        case 7:  p = role_body<7 >(W, xv, w2, w3, w4); break;
        case 8:  p = role_body<8 >(W, xv, w2, w3, w4); break;
        case 9:  p = role_body<9 >(W, xv, w2, w3, w4); break;
        case 10: p = role_body<10>(W, xv, w2, w3, w4); break;
        case 11: p = role_body<11>(W, xv, w2, w3, w4); break;
        case 12: p = role_body<12>(W, xv, w2, w3, w4); break;
        case 13: p = role_body<13>(W, xv, w2, w3, w4); break;
        case 14: p = role_body<14>(W, xv, w2, w3, w4); break;
        default: p = role_body<15>(W, xv, w2, w3, w4); break;
    }

    part[(size_t)role * BATCH + s] = p;          // coalesced 4KB/wave
}

// ---------- kernel 2: combine 16 partials + deg1 + bias, sigmoid ----------
__global__ __launch_bounds__(256)
void finalize_kernel(const float* __restrict__ x, const float* __restrict__ W,
                     const float* __restrict__ b, const float* __restrict__ M_raw,
                     const float* __restrict__ part, float* __restrict__ out)
{
    const int i = blockIdx.x * 256 + threadIdx.x;

    const float4* xp = reinterpret_cast<const float4*>(x + (size_t)i * DIMS);
    const float4 xa = xp[0], xb = xp[1], xc = xp[2], xd = xp[3];

    const float M  = 3.0f/(1.0f+__expf(-M_raw[0])) + 1.0f;
    const float w1 = 1.0f/(1.0f+__expf(-10.0f*(M-0.5f)));

    float xv[DIMS];
    xv[0]=xa.x; xv[1]=xa.y; xv[2]=xa.z; xv[3]=xa.w;
    xv[4]=xb.x; xv[5]=xb.y; xv[6]=xb.z; xv[7]=xb.w;
    xv[8]=xc.x; xv[9]=xc.y; xv[10]=xc.z; xv[11]=xc.w;
    xv[12]=xd.x; xv[13]=xd.y; xv[14]=xd.z; xv[15]=xd.w;

    float s1 = 0.f;
    sfor<DIMS>([&](auto J){ constexpr int j = decltype(J)::value;
        s1 = fmaf(W[1 + j], xv[j], s1); });

    float logit = W[0] + b[0] + w1 * s1;
    #pragma unroll
    for (int r = 0; r < NROLE; ++r)              // fixed order -> deterministic
        logit += part[(size_t)r * BATCH + i];

    out[i] = 1.0f/(1.0f+__expf(-logit));
}

extern "C" void kernel_launch(void* const* d_in, const int* in_sizes, int n_in,
                              void* d_out, int out_size, void* d_ws, size_t ws_size,
                              hipStream_t stream)
{
    const float* x     = (const float*)d_in[0];
    const float* W     = (const float*)d_in[1];
    const float* b     = (const float*)d_in[2];
    const float* M_raw = (const float*)d_in[3];
    float* out  = (float*)d_out;
    float* part = (float*)d_ws;                  // needs NROLE*BATCH*4 = 2 MB

    role_kernel<<<NROLE * (BATCH/1024), 1024, 0, stream>>>(x, W, M_raw, part);
    finalize_kernel<<<BATCH/256, 256, 0, stream>>>(x, W, b, M_raw, part, out);
}